// Round 11
// baseline (186.081 us; speedup 1.0000x reference)
//
#include <hip/hip_runtime.h>
#include <cstdint>
#include <cstddef>
#include <utility>

#define SS 512
#define TT 32
#define NB 256
#define KSTEPS 510  // SS-2
#define PROWS 512   // pstore row stride per batch; row k = partition ENTERING step k

// ---------- unroll helper (compile-time indices -> registers) ----------
template <typename F, size_t... Is>
__device__ __forceinline__ void unroll_impl(F&& f, std::index_sequence<Is...>) {
  (f(std::integral_constant<int, (int)Is>{}), ...);
}
template <int N, typename F>
__device__ __forceinline__ void unrollN(F&& f) {
  unroll_impl(f, std::make_index_sequence<N>{});
}

// butterfly xor D within each 32-lane group (one-time reductions only)
template <int D>
__device__ __forceinline__ float bfly32(float v) {
  return __int_as_float(__builtin_amdgcn_ds_swizzle(__float_as_int(v), (D << 10) | 0x1f));
}
template <int D>
__device__ __forceinline__ int bfly32i(int v) {
  return __builtin_amdgcn_ds_swizzle(v, (D << 10) | 0x1f);
}

__device__ __forceinline__ float max3f(float a, float b, float c) {
  return fmaxf(fmaxf(a, b), c);  // fuses to v_max3_f32; fmax exact in any grouping
}

// exact max of cur[32] via max3 tree (bit-exact: fmax associative)
__device__ __forceinline__ float max32(const float (&cur)[TT]) {
  float t0 = max3f(cur[0], cur[1], cur[2]);
  float t1 = max3f(cur[3], cur[4], cur[5]);
  float t2 = max3f(cur[6], cur[7], cur[8]);
  float t3 = max3f(cur[9], cur[10], cur[11]);
  float t4 = max3f(cur[12], cur[13], cur[14]);
  float t5 = max3f(cur[15], cur[16], cur[17]);
  float t6 = max3f(cur[18], cur[19], cur[20]);
  float t7 = max3f(cur[21], cur[22], cur[23]);
  float t8 = max3f(cur[24], cur[25], cur[26]);
  float t9 = max3f(cur[27], cur[28], cur[29]);
  float ta = fmaxf(cur[30], cur[31]);
  float u0 = max3f(t0, t1, t2);
  float u1 = max3f(t3, t4, t5);
  float u2 = max3f(t6, t7, t8);
  float u3 = fmaxf(t9, ta);
  return fmaxf(fmaxf(u0, u1), fmaxf(u2, u3));
}

// ---------- mask dtype autodetect (bool may arrive as i32 / u8 / f32) ----------
__device__ __forceinline__ int mask_mode(const void* m) {
  int w0 = ((const int*)m)[0];          // element (0,0) is always true (L>=256)
  if (w0 == 1) return 0;                // int32 0/1
  if (w0 == 0x3f800000) return 2;       // float32 1.0
  return 1;                             // uint8
}
__device__ __forceinline__ bool mask_at(const void* m, int idx, int mode) {
  if (mode == 0) return ((const int*)m)[idx] != 0;
  if (mode == 2) return ((const float*)m)[idx] != 0.0f;
  return ((const unsigned char*)m)[idx] != 0;
}

// per-wave sequence length (lane in [0,64))
__device__ __forceinline__ int seq_length_lane(const void* mask, int b, int lane, int mode) {
  int cnt = 0;
  for (int s = lane; s < SS; s += 64) cnt += mask_at(mask, b * SS + s, mode) ? 1 : 0;
  for (int d = 1; d < 64; d <<= 1) cnt += __shfl_xor(cnt, d, 64);
  return cnt;
}

// ---------- K1: 8 independent chains per block (one per wave) ----------
// Blocks 0..31: forward chains (batch = blk*8 + wave).
// Blocks 32..63: viterbi chains (batch = (blk-32)*8 + wave).
// Blocks 64..71: gold score (4 batches per wave).
// 8 waves/CU = 2 chains/SIMD -> LDS-turnaround latencies of co-resident
// chains interleave (TLP), unlike the 1-wave-per-SIMD rounds 1-10.
__global__ __launch_bounds__(512) void crf_main_kernel(
    const float* __restrict__ feats, const float* __restrict__ trans,
    const void* __restrict__ mask, const int* __restrict__ tags,
    float* __restrict__ pstore, float* __restrict__ ws_fwd,
    float* __restrict__ ws_gold, int* __restrict__ ws_ptr) {
  const int blk = blockIdx.x;
  const int tid = threadIdx.x;
  const int wave = tid >> 6;
  const int lane = tid & 63;
  const int j = lane & 31;   // owned tag
  const int mode = mask_mode(mask);

  __shared__ __align__(16) float qlds[8][TT];  // per-wave 128B slice, no cross-wave use

  if (blk < 32) {
    // ========== FORWARD, exp-space: q' = exp(f) * (E^T q), exact 2^k rescale ==========
    const int b = blk * 8 + wave;
    const int L = seq_length_lane(mask, b, lane, mode);
    const int steps = L - 2;
    const float* fb = feats + (size_t)b * (SS * TT) + j;

    float E[TT];  // full column j of exp(trans)
    unrollN<TT>([&](auto I) { constexpr int ii = I; E[ii] = __expf(trans[ii * TT + j]); });

    float q = __expf(fb[TT]);
    int Eacc = 0;
    qlds[wave][j] = q;
    asm volatile("" ::: "memory");
    const float4* qv = (const float4*)qlds[wave];  // uniform address: all-lane broadcast

    float fA = fb[2 * TT], fB = fb[3 * TT], fC = fb[4 * TT];
    float ef = __expf(fA);

    auto fstep = [&](int k, bool resc) {
      float4 Q0 = qv[0], Q1 = qv[1], Q2 = qv[2], Q3 = qv[3];
      float4 Q4 = qv[4], Q5 = qv[5], Q6 = qv[6], Q7 = qv[7];
      int r5 = k + 5; r5 = (r5 < SS) ? r5 : (SS - 1);
      float fD = fb[r5 * TT];                      // prefetch depth-3 (off-chain)
      float efN = __expf(fB);                      // next step's exp (off-chain)
      float a0, a1, a2, a3;
      a0 = Q0.x * E[0];  a1 = Q0.y * E[1];  a2 = Q0.z * E[2];  a3 = Q0.w * E[3];
      a0 = fmaf(Q1.x, E[4], a0);  a1 = fmaf(Q1.y, E[5], a1);  a2 = fmaf(Q1.z, E[6], a2);  a3 = fmaf(Q1.w, E[7], a3);
      a0 = fmaf(Q2.x, E[8], a0);  a1 = fmaf(Q2.y, E[9], a1);  a2 = fmaf(Q2.z, E[10], a2); a3 = fmaf(Q2.w, E[11], a3);
      a0 = fmaf(Q3.x, E[12], a0); a1 = fmaf(Q3.y, E[13], a1); a2 = fmaf(Q3.z, E[14], a2); a3 = fmaf(Q3.w, E[15], a3);
      a0 = fmaf(Q4.x, E[16], a0); a1 = fmaf(Q4.y, E[17], a1); a2 = fmaf(Q4.z, E[18], a2); a3 = fmaf(Q4.w, E[19], a3);
      a0 = fmaf(Q5.x, E[20], a0); a1 = fmaf(Q5.y, E[21], a1); a2 = fmaf(Q5.z, E[22], a2); a3 = fmaf(Q5.w, E[23], a3);
      a0 = fmaf(Q6.x, E[24], a0); a1 = fmaf(Q6.y, E[25], a1); a2 = fmaf(Q6.z, E[26], a2); a3 = fmaf(Q6.w, E[27], a3);
      a0 = fmaf(Q7.x, E[28], a0); a1 = fmaf(Q7.y, E[29], a1); a2 = fmaf(Q7.z, E[30], a2); a3 = fmaf(Q7.w, E[31], a3);
      float P = (a0 + a1) + (a2 + a3);
      q = ef * P;
      if (resc) {
        int e = (__float_as_int(Q0.x) >> 23) & 0xff;   // exponent of q_prev[0], uniform
        Eacc += e - 127;
        q *= __int_as_float((254 - e) << 23);          // exact power-of-two scale
      }
      qlds[wave][j] = q;
      asm volatile("" ::: "memory");
      fA = fB; fB = fC; fC = fD; ef = efN;
    };

    int k = 0;
    for (; k + 4 <= steps; k += 4) {
      fstep(k, false); fstep(k + 1, false); fstep(k + 2, false); fstep(k + 3, true);
    }
    for (; k < steps; ++k) fstep(k, false);

    // forward score = log(sum_j q_j) + Eacc*ln2
    float s = q;
    unrollN<5>([&](auto D) { constexpr int d = 1 << D; s += bfly32<d>(s); });
    if (lane == 0) ws_fwd[b] = __logf(s) + (float)Eacc * 0.69314718056f;

  } else if (blk < 64) {
    // ================= VITERBI (max only; bp deferred to K2) =================
    const int b = (blk - 32) * 8 + wave;
    const int L = seq_length_lane(mask, b, lane, mode);
    const int steps = L - 2;
    const float* fb = feats + (size_t)b * (SS * TT) + j;
    float* pst = pstore + (size_t)b * (PROWS * TT) + j;  // lanes j, j+32 -> same addr

    float C[TT];  // full column j of trans
    unrollN<TT>([&](auto I) { constexpr int ii = I; C[ii] = trans[ii * TT + j]; });

    float p = fb[TT];
    qlds[wave][j] = p;
    asm volatile("" ::: "memory");
    pst[0] = p;                                   // row 0 = initial partition
    const float4* qv = (const float4*)qlds[wave];

    float fA = fb[2 * TT], fB = fb[3 * TT], fC = fb[4 * TT];
    float ddA[TT], ddB[TT];
    unrollN<TT>([&](auto I) { constexpr int ii = I; ddA[ii] = fA + C[ii]; });  // fl(f+tr), step k

    auto vstep = [&](int k, float (&du)[TT], float (&dn)[TT]) {
      float4 Q0 = qv[0], Q1 = qv[1], Q2 = qv[2], Q3 = qv[3];
      float4 Q4 = qv[4], Q5 = qv[5], Q6 = qv[6], Q7 = qv[7];
      // off-chain while reads fly: prefetch + next step's dd (into the OTHER array)
      int r5 = k + 5; r5 = (r5 < SS) ? r5 : (SS - 1);
      float fD = fb[r5 * TT];
      unrollN<TT>([&](auto I) { constexpr int ii = I; dn[ii] = fB + C[ii]; });
      // on-chain: cur_i = fl(p_i + fl(f+tr)) (reference order), exact max tree
      float cur[TT];
      cur[0] = Q0.x + du[0];   cur[1] = Q0.y + du[1];   cur[2] = Q0.z + du[2];   cur[3] = Q0.w + du[3];
      cur[4] = Q1.x + du[4];   cur[5] = Q1.y + du[5];   cur[6] = Q1.z + du[6];   cur[7] = Q1.w + du[7];
      cur[8] = Q2.x + du[8];   cur[9] = Q2.y + du[9];   cur[10] = Q2.z + du[10]; cur[11] = Q2.w + du[11];
      cur[12] = Q3.x + du[12]; cur[13] = Q3.y + du[13]; cur[14] = Q3.z + du[14]; cur[15] = Q3.w + du[15];
      cur[16] = Q4.x + du[16]; cur[17] = Q4.y + du[17]; cur[18] = Q4.z + du[18]; cur[19] = Q4.w + du[19];
      cur[20] = Q5.x + du[20]; cur[21] = Q5.y + du[21]; cur[22] = Q5.z + du[22]; cur[23] = Q5.w + du[23];
      cur[24] = Q6.x + du[24]; cur[25] = Q6.y + du[25]; cur[26] = Q6.z + du[26]; cur[27] = Q6.w + du[27];
      cur[28] = Q7.x + du[28]; cur[29] = Q7.y + du[29]; cur[30] = Q7.z + du[30]; cur[31] = Q7.w + du[31];
      float vmax = max32(cur);
      p = vmax;
      qlds[wave][j] = vmax;              // write ASAP: next read depends on it
      asm volatile("" ::: "memory");
      pst[(k + 1) * TT] = vmax;          // fire-and-forget global (row k+1)
      fA = fB; fB = fC; fC = fD;
    };

    int k = 0;
    for (; k + 2 <= steps; k += 2) { vstep(k, ddA, ddB); vstep(k + 1, ddB, ddA); }
    if (k < steps) vstep(k, ddA, ddB);

    // pointer = first-max argmax over tags of final partition
    float v = p;
    int idx = j;
    unrollN<5>([&](auto D) {
      constexpr int d = 1 << D;
      float vo = bfly32<d>(v);
      int io = bfly32i<d>(idx);
      bool take = (vo > v) || ((vo == v) && (io < idx));
      v = take ? vo : v;
      idx = take ? io : idx;
    });
    if (lane == 0) ws_ptr[b] = idx;

  } else {
    // ================= GOLD SCORE (4 batches per wave) =================
    for (int bb = 0; bb < 4; ++bb) {
      const int b = (blk - 64) * 32 + wave * 4 + bb;
      float acc = 0.0f;
      for (int s = lane; s < SS; s += 64) {
        if (s == 0) continue;
        if (!mask_at(mask, b * SS + s, mode)) continue;
        int tg = tags[b * SS + s];
        if (tg == -100) tg = 0;
        float e = feats[((size_t)b * SS + s) * TT + tg];
        if (s >= 2) {
          int tp = tags[b * SS + s - 1];
          if (tp == -100) tp = 0;
          e += trans[tp * TT + tg];
        }
        acc += e;
      }
      for (int d = 1; d < 64; d <<= 1) acc += __shfl_xor(acc, d, 64);
      if (lane == 0) ws_gold[b] = acc;
    }
  }
}

// ---------- K2: parallel bp recompute + chunked backtrace + finish ----------
__global__ __launch_bounds__(512) void crf_backtrace_kernel(
    const float* __restrict__ pstore, const float* __restrict__ feats,
    const float* __restrict__ trans, const void* __restrict__ mask,
    const int* __restrict__ ws_ptr, const float* __restrict__ ws_fwd,
    const float* __restrict__ ws_gold, float* __restrict__ out) {
  __shared__ unsigned char bp[KSTEPS * TT];     // 16320 B
  __shared__ unsigned char path[KSTEPS * TT];   // 16320 B
  __shared__ int entries[8];

  const int b = blockIdx.x;
  const int tid = threadIdx.x;
  const int mode = mask_mode(mask);
  const int lane = tid & 63;
  float* out_decode = out + 1 + NB;

  const int L = seq_length_lane(mask, b, lane, mode);  // same in every wave
  const int steps = L - 2;

  if (tid == 0) out[1 + b] = 0.0f;  // path_score = zeros(B)
  if (b == 0 && tid >= 64 && tid < 128) {
    int t = tid - 64;
    float sf = 0.0f, sg = 0.0f;
    for (int r = 0; r < 4; ++r) { sf += ws_fwd[t + 64 * r]; sg += ws_gold[t + 64 * r]; }
    for (int d = 1; d < 64; d <<= 1) { sf += __shfl_xor(sf, d, 64); sg += __shfl_xor(sg, d, 64); }
    if (t == 0) out[0] = (sf - sg) / 256.0f;
  }

  // ---- parallel bp recompute: thread (g=tid>>5, jj=tid&31) handles k = g, g+16, ...
  {
    const int jj = tid & 31;
    const int g = tid >> 5;
    float Cc[TT];
    unrollN<TT>([&](auto I) { constexpr int ii = I; Cc[ii] = trans[ii * TT + jj]; });
    const float* pb = pstore + (size_t)b * (PROWS * TT);
    const float* fbb = feats + (size_t)b * (SS * TT);
    for (int k = g; k < KSTEPS; k += 16) {
      if (k < steps) {
        const float4* pr = (const float4*)(pb + k * TT);  // uniform per 32-group
        float4 P0 = pr[0], P1 = pr[1], P2 = pr[2], P3 = pr[3];
        float4 P4 = pr[4], P5 = pr[5], P6 = pr[6], P7 = pr[7];
        float fj = fbb[(k + 2) * TT + jj];
        float cur[TT];  // fl(fl(f+tr) + p): identical floats to K1's chain
        cur[0]  = (fj + Cc[0])  + P0.x; cur[1]  = (fj + Cc[1])  + P0.y;
        cur[2]  = (fj + Cc[2])  + P0.z; cur[3]  = (fj + Cc[3])  + P0.w;
        cur[4]  = (fj + Cc[4])  + P1.x; cur[5]  = (fj + Cc[5])  + P1.y;
        cur[6]  = (fj + Cc[6])  + P1.z; cur[7]  = (fj + Cc[7])  + P1.w;
        cur[8]  = (fj + Cc[8])  + P2.x; cur[9]  = (fj + Cc[9])  + P2.y;
        cur[10] = (fj + Cc[10]) + P2.z; cur[11] = (fj + Cc[11]) + P2.w;
        cur[12] = (fj + Cc[12]) + P3.x; cur[13] = (fj + Cc[13]) + P3.y;
        cur[14] = (fj + Cc[14]) + P3.z; cur[15] = (fj + Cc[15]) + P3.w;
        cur[16] = (fj + Cc[16]) + P4.x; cur[17] = (fj + Cc[17]) + P4.y;
        cur[18] = (fj + Cc[18]) + P4.z; cur[19] = (fj + Cc[19]) + P4.w;
        cur[20] = (fj + Cc[20]) + P5.x; cur[21] = (fj + Cc[21]) + P5.y;
        cur[22] = (fj + Cc[22]) + P5.z; cur[23] = (fj + Cc[23]) + P5.w;
        cur[24] = (fj + Cc[24]) + P6.x; cur[25] = (fj + Cc[25]) + P6.y;
        cur[26] = (fj + Cc[26]) + P6.z; cur[27] = (fj + Cc[27]) + P6.w;
        cur[28] = (fj + Cc[28]) + P7.x; cur[29] = (fj + Cc[29]) + P7.y;
        cur[30] = (fj + Cc[30]) + P7.z; cur[31] = (fj + Cc[31]) + P7.w;
        float vmax = max32(cur);
        int bi = 31;  // first-max (descending overwrite-on-equal = jnp.argmax)
        unrollN<TT>([&](auto I) { constexpr int ii = 31 - I; bi = (cur[ii] == vmax) ? ii : bi; });
        bp[k * TT + jj] = (unsigned char)bi;
      } else {
        bp[k * TT + jj] = 0;  // reference masks bps to 0 beyond steps
      }
    }
  }
  __syncthreads();

  // ---- chunked-hypothesis backtrace (each wave = one 64-step chunk)
  const int wave = tid >> 6;
  if (lane < 32) {
    const int lo = wave * 64;
    const int hi = (lo + 64 < KSTEPS) ? (lo + 64) : KSTEPS;
    int ptr = lane;
    for (int k = hi - 1; k >= lo; --k) {
      ptr = bp[k * TT + ptr];
      path[k * TT + lane] = (unsigned char)ptr;
    }
  }
  __syncthreads();

  // compose chunk entries from the top (chunk 7 enters with pointer)
  if (tid == 0) {
    int e = ws_ptr[b];
    for (int c = 7; c >= 0; --c) {
      entries[c] = e;
      e = path[(c * 64) * TT + e];
    }
  }
  __syncthreads();

  // decode row: [0, ptrs[0..509], pointer]
  const int s = tid;
  int val;
  if (s == 0) val = 0;
  else if (s <= KSTEPS) { int k = s - 1; val = path[k * TT + entries[k >> 6]]; }
  else val = ws_ptr[b];
  out_decode[(size_t)b * SS + s] = (float)val;
}

extern "C" void kernel_launch(void* const* d_in, const int* in_sizes, int n_in,
                              void* d_out, int out_size, void* d_ws, size_t ws_size,
                              hipStream_t stream) {
  const float* feats = (const float*)d_in[0];
  const float* trans = (const float*)d_in[1];
  const void* mask = d_in[2];
  const int* tags = (const int*)d_in[3];
  float* out = (float*)d_out;

  unsigned char* ws = (unsigned char*)d_ws;
  const size_t PST_BYTES = (size_t)NB * PROWS * TT * 4;  // 16,777,216
  float* pstore = (float*)ws;
  float* ws_fwd = (float*)(ws + PST_BYTES);
  float* ws_gold = (float*)(ws + PST_BYTES + 2048);
  int* ws_ptr = (int*)(ws + PST_BYTES + 4096);

  hipLaunchKernelGGL(crf_main_kernel, dim3(72), dim3(512), 0, stream,
                     feats, trans, mask, tags, pstore, ws_fwd, ws_gold, ws_ptr);
  hipLaunchKernelGGL(crf_backtrace_kernel, dim3(NB), dim3(512), 0, stream,
                     pstore, feats, trans, mask, ws_ptr, ws_fwd, ws_gold, out);
}

// Round 12
// 154.473 us; speedup vs baseline: 1.2046x; 1.2046x over previous
//
#include <hip/hip_runtime.h>
#include <cstdint>
#include <cstddef>
#include <utility>

#define SS 512
#define TT 32
#define NB 256
#define KSTEPS 510  // SS-2
#define PROWS 512   // pstore row stride per batch; row k = partition ENTERING step k

// ---------- unroll helper (compile-time indices -> registers) ----------
template <typename F, size_t... Is>
__device__ __forceinline__ void unroll_impl(F&& f, std::index_sequence<Is...>) {
  (f(std::integral_constant<int, (int)Is>{}), ...);
}
template <int N, typename F>
__device__ __forceinline__ void unrollN(F&& f) {
  unroll_impl(f, std::make_index_sequence<N>{});
}

// butterfly xor D within each 32-lane group (one-time reductions only)
template <int D>
__device__ __forceinline__ float bfly32(float v) {
  return __int_as_float(__builtin_amdgcn_ds_swizzle(__float_as_int(v), (D << 10) | 0x1f));
}
template <int D>
__device__ __forceinline__ int bfly32i(int v) {
  return __builtin_amdgcn_ds_swizzle(v, (D << 10) | 0x1f);
}

__device__ __forceinline__ float max3f(float a, float b, float c) {
  return fmaxf(fmaxf(a, b), c);  // fuses to v_max3_f32; fmax exact in any grouping
}

// exact max of cur[32] via max3 tree (bit-exact: fmax associative)
__device__ __forceinline__ float max32(const float (&cur)[TT]) {
  float t0 = max3f(cur[0], cur[1], cur[2]);
  float t1 = max3f(cur[3], cur[4], cur[5]);
  float t2 = max3f(cur[6], cur[7], cur[8]);
  float t3 = max3f(cur[9], cur[10], cur[11]);
  float t4 = max3f(cur[12], cur[13], cur[14]);
  float t5 = max3f(cur[15], cur[16], cur[17]);
  float t6 = max3f(cur[18], cur[19], cur[20]);
  float t7 = max3f(cur[21], cur[22], cur[23]);
  float t8 = max3f(cur[24], cur[25], cur[26]);
  float t9 = max3f(cur[27], cur[28], cur[29]);
  float ta = fmaxf(cur[30], cur[31]);
  float u0 = max3f(t0, t1, t2);
  float u1 = max3f(t3, t4, t5);
  float u2 = max3f(t6, t7, t8);
  float u3 = fmaxf(t9, ta);
  return fmaxf(fmaxf(u0, u1), fmaxf(u2, u3));
}

// ---------- mask dtype autodetect (bool may arrive as i32 / u8 / f32) ----------
__device__ __forceinline__ int mask_mode(const void* m) {
  int w0 = ((const int*)m)[0];          // element (0,0) is always true (L>=256)
  if (w0 == 1) return 0;                // int32 0/1
  if (w0 == 0x3f800000) return 2;       // float32 1.0
  return 1;                             // uint8
}
__device__ __forceinline__ bool mask_at(const void* m, int idx, int mode) {
  if (mode == 0) return ((const int*)m)[idx] != 0;
  if (mode == 2) return ((const float*)m)[idx] != 0.0f;
  return ((const unsigned char*)m)[idx] != 0;
}

// per-wave sequence length (lane in [0,64))
__device__ __forceinline__ int seq_length_lane(const void* mask, int b, int lane, int mode) {
  int cnt = 0;
  for (int s = lane; s < SS; s += 64) cnt += mask_at(mask, b * SS + s, mode) ? 1 : 0;
  for (int d = 1; d < 64; d <<= 1) cnt += __shfl_xor(cnt, d, 64);
  return cnt;
}

// ---------- K1: fused forward / viterbi / gold (role by blockIdx) ----------
// One wave per chain (768 blocks). __launch_bounds__(64,1) unlocks the full
// VGPR budget: rounds 1-11 were silently capped at 64 VGPRs (8-wave/SIMD
// default), forcing remat/spill traffic inside the serial hot loop.
__global__ __launch_bounds__(64, 1) void crf_main_kernel(
    const float* __restrict__ feats, const float* __restrict__ trans,
    const void* __restrict__ mask, const int* __restrict__ tags,
    float* __restrict__ pstore, float* __restrict__ ws_fwd,
    float* __restrict__ ws_gold, int* __restrict__ ws_ptr) {
  const int blk = blockIdx.x;
  const int tid = threadIdx.x;
  const int mode = mask_mode(mask);
  const int j = tid & 31;   // owned tag

  __shared__ __align__(16) float qlds[TT];

  if (blk < NB) {
    // ========== FORWARD, exp-space: q' = exp(f) * (E^T q), exact 2^k rescale ==========
    const int b = blk;
    const int L = seq_length_lane(mask, b, tid, mode);
    const int steps = L - 2;
    const float* fb = feats + (size_t)b * (SS * TT) + j;

    float E[TT];  // full column j of exp(trans)
    unrollN<TT>([&](auto I) { constexpr int ii = I; E[ii] = __expf(trans[ii * TT + j]); });

    float q = __expf(fb[TT]);
    int Eacc = 0;
    qlds[j] = q;
    asm volatile("" ::: "memory");
    const float4* qv = (const float4*)qlds;  // uniform address: all-lane broadcast

    float fA = fb[2 * TT], fB = fb[3 * TT], fC = fb[4 * TT];
    float ef = __expf(fA);

    auto fstep = [&](int k, bool resc) {
      float4 Q0 = qv[0], Q1 = qv[1], Q2 = qv[2], Q3 = qv[3];
      float4 Q4 = qv[4], Q5 = qv[5], Q6 = qv[6], Q7 = qv[7];
      int r5 = k + 5; r5 = (r5 < SS) ? r5 : (SS - 1);
      float fD = fb[r5 * TT];                      // prefetch depth-3 (off-chain)
      float efN = __expf(fB);                      // next step's exp (off-chain)
      float a0, a1, a2, a3;
      a0 = Q0.x * E[0];  a1 = Q0.y * E[1];  a2 = Q0.z * E[2];  a3 = Q0.w * E[3];
      a0 = fmaf(Q1.x, E[4], a0);  a1 = fmaf(Q1.y, E[5], a1);  a2 = fmaf(Q1.z, E[6], a2);  a3 = fmaf(Q1.w, E[7], a3);
      a0 = fmaf(Q2.x, E[8], a0);  a1 = fmaf(Q2.y, E[9], a1);  a2 = fmaf(Q2.z, E[10], a2); a3 = fmaf(Q2.w, E[11], a3);
      a0 = fmaf(Q3.x, E[12], a0); a1 = fmaf(Q3.y, E[13], a1); a2 = fmaf(Q3.z, E[14], a2); a3 = fmaf(Q3.w, E[15], a3);
      a0 = fmaf(Q4.x, E[16], a0); a1 = fmaf(Q4.y, E[17], a1); a2 = fmaf(Q4.z, E[18], a2); a3 = fmaf(Q4.w, E[19], a3);
      a0 = fmaf(Q5.x, E[20], a0); a1 = fmaf(Q5.y, E[21], a1); a2 = fmaf(Q5.z, E[22], a2); a3 = fmaf(Q5.w, E[23], a3);
      a0 = fmaf(Q6.x, E[24], a0); a1 = fmaf(Q6.y, E[25], a1); a2 = fmaf(Q6.z, E[26], a2); a3 = fmaf(Q6.w, E[27], a3);
      a0 = fmaf(Q7.x, E[28], a0); a1 = fmaf(Q7.y, E[29], a1); a2 = fmaf(Q7.z, E[30], a2); a3 = fmaf(Q7.w, E[31], a3);
      float P = (a0 + a1) + (a2 + a3);
      q = ef * P;
      if (resc) {
        int e = (__float_as_int(Q0.x) >> 23) & 0xff;   // exponent of q_prev[0], uniform
        Eacc += e - 127;
        q *= __int_as_float((254 - e) << 23);          // exact power-of-two scale
      }
      qlds[j] = q;
      asm volatile("" ::: "memory");
      fA = fB; fB = fC; fC = fD; ef = efN;
    };

    int k = 0;
    for (; k + 4 <= steps; k += 4) {
      fstep(k, false); fstep(k + 1, false); fstep(k + 2, false); fstep(k + 3, true);
    }
    for (; k < steps; ++k) fstep(k, false);

    // forward score = log(sum_j q_j) + Eacc*ln2
    float s = q;
    unrollN<5>([&](auto D) { constexpr int d = 1 << D; s += bfly32<d>(s); });
    if (tid == 0) ws_fwd[b] = __logf(s) + (float)Eacc * 0.69314718056f;

  } else if (blk < 2 * NB) {
    // ================= VITERBI (max only; bp deferred to K2) =================
    const int b = blk - NB;
    const int L = seq_length_lane(mask, b, tid, mode);
    const int steps = L - 2;
    const float* fb = feats + (size_t)b * (SS * TT) + j;
    float* pst = pstore + (size_t)b * (PROWS * TT) + j;  // lanes j, j+32 -> same addr

    float C[TT];  // full column j of trans
    unrollN<TT>([&](auto I) { constexpr int ii = I; C[ii] = trans[ii * TT + j]; });

    float p = fb[TT];
    qlds[j] = p;
    asm volatile("" ::: "memory");
    pst[0] = p;                                   // row 0 = initial partition
    const float4* qv = (const float4*)qlds;

    float fA = fb[2 * TT], fB = fb[3 * TT], fC = fb[4 * TT];

    auto vstep = [&](int k) {
      float4 Q0 = qv[0], Q1 = qv[1], Q2 = qv[2], Q3 = qv[3];
      float4 Q4 = qv[4], Q5 = qv[5], Q6 = qv[6], Q7 = qv[7];
      // off-chain while reads fly: prefetch + dd = fl(f+tr) (scheduler overlaps)
      int r5 = k + 5; r5 = (r5 < SS) ? r5 : (SS - 1);
      float fD = fb[r5 * TT];
      float dd[TT];
      unrollN<TT>([&](auto I) { constexpr int ii = I; dd[ii] = fA + C[ii]; });
      // on-chain: cur_i = fl(p_i + fl(f+tr)) (reference order), exact max tree
      float cur[TT];
      cur[0] = Q0.x + dd[0];   cur[1] = Q0.y + dd[1];   cur[2] = Q0.z + dd[2];   cur[3] = Q0.w + dd[3];
      cur[4] = Q1.x + dd[4];   cur[5] = Q1.y + dd[5];   cur[6] = Q1.z + dd[6];   cur[7] = Q1.w + dd[7];
      cur[8] = Q2.x + dd[8];   cur[9] = Q2.y + dd[9];   cur[10] = Q2.z + dd[10]; cur[11] = Q2.w + dd[11];
      cur[12] = Q3.x + dd[12]; cur[13] = Q3.y + dd[13]; cur[14] = Q3.z + dd[14]; cur[15] = Q3.w + dd[15];
      cur[16] = Q4.x + dd[16]; cur[17] = Q4.y + dd[17]; cur[18] = Q4.z + dd[18]; cur[19] = Q4.w + dd[19];
      cur[20] = Q5.x + dd[20]; cur[21] = Q5.y + dd[21]; cur[22] = Q5.z + dd[22]; cur[23] = Q5.w + dd[23];
      cur[24] = Q6.x + dd[24]; cur[25] = Q6.y + dd[25]; cur[26] = Q6.z + dd[26]; cur[27] = Q6.w + dd[27];
      cur[28] = Q7.x + dd[28]; cur[29] = Q7.y + dd[29]; cur[30] = Q7.z + dd[30]; cur[31] = Q7.w + dd[31];
      float vmax = max32(cur);
      p = vmax;
      qlds[j] = vmax;                    // write ASAP: next read depends on it
      asm volatile("" ::: "memory");
      pst[(k + 1) * TT] = vmax;          // fire-and-forget global (row k+1)
      fA = fB; fB = fC; fC = fD;
    };

    int k = 0;
    for (; k + 2 <= steps; k += 2) { vstep(k); vstep(k + 1); }
    if (k < steps) vstep(k);

    // pointer = first-max argmax over tags of final partition
    float v = p;
    int idx = j;
    unrollN<5>([&](auto D) {
      constexpr int d = 1 << D;
      float vo = bfly32<d>(v);
      int io = bfly32i<d>(idx);
      bool take = (vo > v) || ((vo == v) && (io < idx));
      v = take ? vo : v;
      idx = take ? io : idx;
    });
    if (tid == 0) ws_ptr[b] = idx;

  } else {
    // ================= GOLD SCORE =================
    const int b = blk - 2 * NB;
    float acc = 0.0f;
    for (int s = tid; s < SS; s += 64) {
      if (s == 0) continue;
      if (!mask_at(mask, b * SS + s, mode)) continue;
      int tg = tags[b * SS + s];
      if (tg == -100) tg = 0;
      float e = feats[((size_t)b * SS + s) * TT + tg];
      if (s >= 2) {
        int tp = tags[b * SS + s - 1];
        if (tp == -100) tp = 0;
        e += trans[tp * TT + tg];
      }
      acc += e;
    }
    for (int d = 1; d < 64; d <<= 1) acc += __shfl_xor(acc, d, 64);
    if (tid == 0) ws_gold[b] = acc;
  }
}

// ---------- K2: parallel bp recompute + chunked backtrace + finish ----------
__global__ __launch_bounds__(512) void crf_backtrace_kernel(
    const float* __restrict__ pstore, const float* __restrict__ feats,
    const float* __restrict__ trans, const void* __restrict__ mask,
    const int* __restrict__ ws_ptr, const float* __restrict__ ws_fwd,
    const float* __restrict__ ws_gold, float* __restrict__ out) {
  __shared__ unsigned char bp[KSTEPS * TT];     // 16320 B
  __shared__ unsigned char path[KSTEPS * TT];   // 16320 B
  __shared__ int entries[8];

  const int b = blockIdx.x;
  const int tid = threadIdx.x;
  const int mode = mask_mode(mask);
  const int lane = tid & 63;
  float* out_decode = out + 1 + NB;

  const int L = seq_length_lane(mask, b, lane, mode);  // same in every wave
  const int steps = L - 2;

  if (tid == 0) out[1 + b] = 0.0f;  // path_score = zeros(B)
  if (b == 0 && tid >= 64 && tid < 128) {
    int t = tid - 64;
    float sf = 0.0f, sg = 0.0f;
    for (int r = 0; r < 4; ++r) { sf += ws_fwd[t + 64 * r]; sg += ws_gold[t + 64 * r]; }
    for (int d = 1; d < 64; d <<= 1) { sf += __shfl_xor(sf, d, 64); sg += __shfl_xor(sg, d, 64); }
    if (t == 0) out[0] = (sf - sg) / 256.0f;
  }

  // ---- parallel bp recompute: thread (g=tid>>5, jj=tid&31) handles k = g, g+16, ...
  {
    const int jj = tid & 31;
    const int g = tid >> 5;
    float Cc[TT];
    unrollN<TT>([&](auto I) { constexpr int ii = I; Cc[ii] = trans[ii * TT + jj]; });
    const float* pb = pstore + (size_t)b * (PROWS * TT);
    const float* fbb = feats + (size_t)b * (SS * TT);
    for (int k = g; k < KSTEPS; k += 16) {
      if (k < steps) {
        const float4* pr = (const float4*)(pb + k * TT);  // uniform per 32-group
        float4 P0 = pr[0], P1 = pr[1], P2 = pr[2], P3 = pr[3];
        float4 P4 = pr[4], P5 = pr[5], P6 = pr[6], P7 = pr[7];
        float fj = fbb[(k + 2) * TT + jj];
        float cur[TT];  // fl(fl(f+tr) + p): identical floats to K1's chain
        cur[0]  = (fj + Cc[0])  + P0.x; cur[1]  = (fj + Cc[1])  + P0.y;
        cur[2]  = (fj + Cc[2])  + P0.z; cur[3]  = (fj + Cc[3])  + P0.w;
        cur[4]  = (fj + Cc[4])  + P1.x; cur[5]  = (fj + Cc[5])  + P1.y;
        cur[6]  = (fj + Cc[6])  + P1.z; cur[7]  = (fj + Cc[7])  + P1.w;
        cur[8]  = (fj + Cc[8])  + P2.x; cur[9]  = (fj + Cc[9])  + P2.y;
        cur[10] = (fj + Cc[10]) + P2.z; cur[11] = (fj + Cc[11]) + P2.w;
        cur[12] = (fj + Cc[12]) + P3.x; cur[13] = (fj + Cc[13]) + P3.y;
        cur[14] = (fj + Cc[14]) + P3.z; cur[15] = (fj + Cc[15]) + P3.w;
        cur[16] = (fj + Cc[16]) + P4.x; cur[17] = (fj + Cc[17]) + P4.y;
        cur[18] = (fj + Cc[18]) + P4.z; cur[19] = (fj + Cc[19]) + P4.w;
        cur[20] = (fj + Cc[20]) + P5.x; cur[21] = (fj + Cc[21]) + P5.y;
        cur[22] = (fj + Cc[22]) + P5.z; cur[23] = (fj + Cc[23]) + P5.w;
        cur[24] = (fj + Cc[24]) + P6.x; cur[25] = (fj + Cc[25]) + P6.y;
        cur[26] = (fj + Cc[26]) + P6.z; cur[27] = (fj + Cc[27]) + P6.w;
        cur[28] = (fj + Cc[28]) + P7.x; cur[29] = (fj + Cc[29]) + P7.y;
        cur[30] = (fj + Cc[30]) + P7.z; cur[31] = (fj + Cc[31]) + P7.w;
        float vmax = max32(cur);
        int bi = 31;  // first-max (descending overwrite-on-equal = jnp.argmax)
        unrollN<TT>([&](auto I) { constexpr int ii = 31 - I; bi = (cur[ii] == vmax) ? ii : bi; });
        bp[k * TT + jj] = (unsigned char)bi;
      } else {
        bp[k * TT + jj] = 0;  // reference masks bps to 0 beyond steps
      }
    }
  }
  __syncthreads();

  // ---- chunked-hypothesis backtrace (each wave = one 64-step chunk)
  const int wave = tid >> 6;
  if (lane < 32) {
    const int lo = wave * 64;
    const int hi = (lo + 64 < KSTEPS) ? (lo + 64) : KSTEPS;
    int ptr = lane;
    for (int k = hi - 1; k >= lo; --k) {
      ptr = bp[k * TT + ptr];
      path[k * TT + lane] = (unsigned char)ptr;
    }
  }
  __syncthreads();

  // compose chunk entries from the top (chunk 7 enters with pointer)
  if (tid == 0) {
    int e = ws_ptr[b];
    for (int c = 7; c >= 0; --c) {
      entries[c] = e;
      e = path[(c * 64) * TT + e];
    }
  }
  __syncthreads();

  // decode row: [0, ptrs[0..509], pointer]
  const int s = tid;
  int val;
  if (s == 0) val = 0;
  else if (s <= KSTEPS) { int k = s - 1; val = path[k * TT + entries[k >> 6]]; }
  else val = ws_ptr[b];
  out_decode[(size_t)b * SS + s] = (float)val;
}

extern "C" void kernel_launch(void* const* d_in, const int* in_sizes, int n_in,
                              void* d_out, int out_size, void* d_ws, size_t ws_size,
                              hipStream_t stream) {
  const float* feats = (const float*)d_in[0];
  const float* trans = (const float*)d_in[1];
  const void* mask = d_in[2];
  const int* tags = (const int*)d_in[3];
  float* out = (float*)d_out;

  unsigned char* ws = (unsigned char*)d_ws;
  const size_t PST_BYTES = (size_t)NB * PROWS * TT * 4;  // 16,777,216
  float* pstore = (float*)ws;
  float* ws_fwd = (float*)(ws + PST_BYTES);
  float* ws_gold = (float*)(ws + PST_BYTES + 2048);
  int* ws_ptr = (int*)(ws + PST_BYTES + 4096);

  hipLaunchKernelGGL(crf_main_kernel, dim3(3 * NB), dim3(64), 0, stream,
                     feats, trans, mask, tags, pstore, ws_fwd, ws_gold, ws_ptr);
  hipLaunchKernelGGL(crf_backtrace_kernel, dim3(NB), dim3(512), 0, stream,
                     pstore, feats, trans, mask, ws_ptr, ws_fwd, ws_gold, out);
}

// Round 14
// 110.805 us; speedup vs baseline: 1.6794x; 1.3941x over previous
//
#include <hip/hip_runtime.h>
#include <cstdint>
#include <cstddef>
#include <utility>

#define SS 512
#define TT 32
#define NB 256
#define KSTEPS 510   // SS-2
#define PQUADS 128   // pstore quads per batch (4 rows each)

// ---------- unroll helper (compile-time indices -> registers) ----------
template <typename F, size_t... Is>
__device__ __forceinline__ void unroll_impl(F&& f, std::index_sequence<Is...>) {
  (f(std::integral_constant<int, (int)Is>{}), ...);
}
template <int N, typename F>
__device__ __forceinline__ void unrollN(F&& f) {
  unroll_impl(f, std::make_index_sequence<N>{});
}

// butterfly xor D within each 32-lane group (one-time reductions only)
template <int D>
__device__ __forceinline__ float bfly32(float v) {
  return __int_as_float(__builtin_amdgcn_ds_swizzle(__float_as_int(v), (D << 10) | 0x1f));
}
template <int D>
__device__ __forceinline__ int bfly32i(int v) {
  return __builtin_amdgcn_ds_swizzle(v, (D << 10) | 0x1f);
}

__device__ __forceinline__ float max3f(float a, float b, float c) {
  return fmaxf(fmaxf(a, b), c);  // fuses to v_max3_f32; fmax exact in any grouping
}

// ---- cross-half combine, orientation-proof ----
// permlane32_swap with BOTH operands = m returns, per lane, the pair
// {own value, partner(lane^32) value} in SOME order (either row-swap
// convention). max/sum of the two words is therefore exact and
// convention-independent. No inline asm, no orientation probe.
__device__ __forceinline__ float combine_max32(float m) {
#if __has_builtin(__builtin_amdgcn_permlane32_swap)
  auto r = __builtin_amdgcn_permlane32_swap(__float_as_uint(m), __float_as_uint(m), false, false);
  return fmaxf(__uint_as_float(r[0]), __uint_as_float(r[1]));
#else
  return fmaxf(m, __shfl_xor(m, 32, 64));
#endif
}
__device__ __forceinline__ float combine_sum32(float m) {
#if __has_builtin(__builtin_amdgcn_permlane32_swap)
  auto r = __builtin_amdgcn_permlane32_swap(__float_as_uint(m), __float_as_uint(m), false, false);
  return __uint_as_float(r[0]) + __uint_as_float(r[1]);
#else
  return m + __shfl_xor(m, 32, 64);
#endif
}

// ---------- mask dtype autodetect (bool may arrive as i32 / u8 / f32) ----------
__device__ __forceinline__ int mask_mode(const void* m) {
  int w0 = ((const int*)m)[0];          // element (0,0) is always true (L>=256)
  if (w0 == 1) return 0;                // int32 0/1
  if (w0 == 0x3f800000) return 2;       // float32 1.0
  return 1;                             // uint8
}
__device__ __forceinline__ bool mask_at(const void* m, int idx, int mode) {
  if (mode == 0) return ((const int*)m)[idx] != 0;
  if (mode == 2) return ((const float*)m)[idx] != 0.0f;
  return ((const unsigned char*)m)[idx] != 0;
}

// per-wave sequence length (lane in [0,64))
__device__ __forceinline__ int seq_length_lane(const void* mask, int b, int lane, int mode) {
  int cnt = 0;
  for (int s = lane; s < SS; s += 64) cnt += mask_at(mask, b * SS + s, mode) ? 1 : 0;
  for (int d = 1; d < 64; d <<= 1) cnt += __shfl_xor(cnt, d, 64);
  return cnt;
}

// ---------- K1: fused forward / viterbi / gold (role by blockIdx) ----------
// Lane l owns tag j=l&31; half h=l>>5 reduces sources i in [16h,16h+16).
// Per step: 4 uniform-per-half ds_read_b128 (2 addrs/wave = free broadcast)
// -> 16 VALU -> max tree / dot -> permlane32_swap combine (VALU) ->
// 1 ds_write_b32 (2-way same value, benign). Viterbi streams partition rows
// to global in 4-row float4 batches; K2 recomputes backpointers bit-exactly.
__global__ __launch_bounds__(64, 1) void crf_main_kernel(
    const float* __restrict__ feats, const float* __restrict__ trans,
    const void* __restrict__ mask, const int* __restrict__ tags,
    float* __restrict__ pstore, float* __restrict__ ws_fwd,
    float* __restrict__ ws_gold, int* __restrict__ ws_ptr) {
  const int blk = blockIdx.x;
  const int tid = threadIdx.x;
  const int mode = mask_mode(mask);
  const int j = tid & 31;   // owned tag
  const int h = tid >> 5;   // source half

  __shared__ __align__(16) float qlds[TT];

  if (blk < NB) {
    // ========== FORWARD, exp-space: q' = exp(f) * (E^T q), exact 2^k rescale ==========
    const int b = blk;
    const int L = seq_length_lane(mask, b, tid, mode);
    const int steps = L - 2;
    const float* fb = feats + (size_t)b * (SS * TT) + j;

    float E[16];  // rows 16h..16h+15 of exp(trans), column j
    unrollN<16>([&](auto I) {
      constexpr int ii = I;
      E[ii] = __expf(trans[(h * 16 + ii) * TT + j]);
    });

    float q = __expf(fb[TT]);
    int Eacc = 0;
    qlds[j] = q;
    asm volatile("" ::: "memory");
    const float4* qvh = (const float4*)qlds + h * 4;  // own half's 64B

    float fA = fb[2 * TT], fB = fb[3 * TT], fC = fb[4 * TT];
    float ef = __expf(fA);

    auto fstep = [&](int k, bool resc) {
      float4 Q0 = qvh[0], Q1 = qvh[1], Q2 = qvh[2], Q3 = qvh[3];
      int r5 = k + 5; r5 = (r5 < SS) ? r5 : (SS - 1);
      float fD = fb[r5 * TT];                      // prefetch depth-3 (off-chain)
      float efN = __expf(fB);                      // next step's exp (off-chain)
      float a0, a1, a2, a3;
      a0 = Q0.x * E[0];  a1 = Q0.y * E[1];  a2 = Q0.z * E[2];  a3 = Q0.w * E[3];
      a0 = fmaf(Q1.x, E[4], a0);  a1 = fmaf(Q1.y, E[5], a1);  a2 = fmaf(Q1.z, E[6], a2);  a3 = fmaf(Q1.w, E[7], a3);
      a0 = fmaf(Q2.x, E[8], a0);  a1 = fmaf(Q2.y, E[9], a1);  a2 = fmaf(Q2.z, E[10], a2); a3 = fmaf(Q2.w, E[11], a3);
      a0 = fmaf(Q3.x, E[12], a0); a1 = fmaf(Q3.y, E[13], a1); a2 = fmaf(Q3.z, E[14], a2); a3 = fmaf(Q3.w, E[15], a3);
      float P = (a0 + a1) + (a2 + a3);             // own-half partial dot
      float Pt = combine_sum32(P);                 // full dot (bitwise same both halves)
      q = ef * Pt;
      if (resc) {
        int qb = __builtin_amdgcn_readfirstlane(__float_as_int(q));  // q[0], uniform
        int e = (qb >> 23) & 0xff;
        Eacc += e - 127;
        q *= __int_as_float((254 - e) << 23);      // exact power-of-two scale
      }
      qlds[j] = q;
      asm volatile("" ::: "memory");
      fA = fB; fB = fC; fC = fD; ef = efN;
    };

    int k = 0;
    for (; k + 4 <= steps; k += 4) {
      fstep(k, false); fstep(k + 1, false); fstep(k + 2, false); fstep(k + 3, true);
    }
    for (; k < steps; ++k) fstep(k, false);

    // forward score = log(sum_j q_j) + Eacc*ln2
    float s = q;
    unrollN<5>([&](auto D) { constexpr int d = 1 << D; s += bfly32<d>(s); });
    if (tid == 0) ws_fwd[b] = __logf(s) + (float)Eacc * 0.69314718056f;

  } else if (blk < 2 * NB) {
    // ================= VITERBI (max only; bp deferred to K2) =================
    const int b = blk - NB;
    const int L = seq_length_lane(mask, b, tid, mode);
    const int steps = L - 2;
    const float* fb = feats + (size_t)b * (SS * TT) + j;
    float* pq = pstore + (size_t)b * (PQUADS * 128) + j * 4;  // lane j's 16B slot

    float C[16];  // rows 16h..16h+15 of trans, column j
    unrollN<16>([&](auto I) {
      constexpr int ii = I;
      C[ii] = trans[(h * 16 + ii) * TT + j];
    });

    float p = fb[TT];
    qlds[j] = p;
    asm volatile("" ::: "memory");
    const float4* qvh = (const float4*)qlds + h * 4;

    float fA = fb[2 * TT], fB = fb[3 * TT], fC = fb[4 * TT];
    float h0 = p, h1 = 0.f, h2 = 0.f, h3 = 0.f;  // row history (row r in slot r&3)

    auto vstep = [&](int k, float& hslot) {
      float4 Q0 = qvh[0], Q1 = qvh[1], Q2 = qvh[2], Q3 = qvh[3];
      int r5 = k + 5; r5 = (r5 < SS) ? r5 : (SS - 1);
      float fD = fb[r5 * TT];
      float dd[16];
      unrollN<16>([&](auto I) { constexpr int ii = I; dd[ii] = fA + C[ii]; });  // fl(f+tr)
      float cur[16];  // fl(fl(f+tr) + p): reference op order
      cur[0] = Q0.x + dd[0];   cur[1] = Q0.y + dd[1];   cur[2] = Q0.z + dd[2];   cur[3] = Q0.w + dd[3];
      cur[4] = Q1.x + dd[4];   cur[5] = Q1.y + dd[5];   cur[6] = Q1.z + dd[6];   cur[7] = Q1.w + dd[7];
      cur[8] = Q2.x + dd[8];   cur[9] = Q2.y + dd[9];   cur[10] = Q2.z + dd[10]; cur[11] = Q2.w + dd[11];
      cur[12] = Q3.x + dd[12]; cur[13] = Q3.y + dd[13]; cur[14] = Q3.z + dd[14]; cur[15] = Q3.w + dd[15];
      float t0 = max3f(cur[0], cur[1], cur[2]);
      float t1 = max3f(cur[3], cur[4], cur[5]);
      float t2 = max3f(cur[6], cur[7], cur[8]);
      float t3 = max3f(cur[9], cur[10], cur[11]);
      float t4 = max3f(cur[12], cur[13], cur[14]);
      float m = fmaxf(max3f(t0, t1, t2), max3f(t3, t4, cur[15]));  // own-half max
      float pw = combine_max32(m);                 // full 32-source max (exact)
      p = pw;
      qlds[j] = pw;                                // write ASAP: next read depends on it
      asm volatile("" ::: "memory");
      hslot = pw;
      fA = fB; fB = fC; fC = fD;
    };

    auto flush = [&](int quad) {
      if (tid < 32) {
        float4 v; v.x = h0; v.y = h1; v.z = h2; v.w = h3;
        *(float4*)(pq + quad * 128) = v;
      }
    };

    int k = 0;
    for (; k + 4 <= steps; k += 4) {
      vstep(k, h1);        // row k+1
      vstep(k + 1, h2);    // row k+2
      vstep(k + 2, h3);    // row k+3
      flush(k >> 2);       // rows k..k+3
      vstep(k + 3, h0);    // row k+4 (next quad slot 0)
    }
    if (k < steps) vstep(k, h1);
    if (k + 1 < steps) vstep(k + 1, h2);
    if (k + 2 < steps) vstep(k + 2, h3);
    flush(k >> 2);         // tail rows (K2 guards k < steps)

    // pointer = first-max argmax over tags of final partition
    float v = p;
    int idx = j;
    unrollN<5>([&](auto D) {
      constexpr int d = 1 << D;
      float vo = bfly32<d>(v);
      int io = bfly32i<d>(idx);
      bool take = (vo > v) || ((vo == v) && (io < idx));
      v = take ? vo : v;
      idx = take ? io : idx;
    });
    if (tid == 0) ws_ptr[b] = idx;

  } else {
    // ================= GOLD SCORE =================
    const int b = blk - 2 * NB;
    float acc = 0.0f;
    for (int s = tid; s < SS; s += 64) {
      if (s == 0) continue;
      if (!mask_at(mask, b * SS + s, mode)) continue;
      int tg = tags[b * SS + s];
      if (tg == -100) tg = 0;
      float e = feats[((size_t)b * SS + s) * TT + tg];
      if (s >= 2) {
        int tp = tags[b * SS + s - 1];
        if (tp == -100) tp = 0;
        e += trans[tp * TT + tg];
      }
      acc += e;
    }
    for (int d = 1; d < 64; d <<= 1) acc += __shfl_xor(acc, d, 64);
    if (tid == 0) ws_gold[b] = acc;
  }
}

// ---------- K2: parallel bp recompute + chunked backtrace + finish ----------
__global__ __launch_bounds__(512) void crf_backtrace_kernel(
    const float* __restrict__ pstore, const float* __restrict__ feats,
    const float* __restrict__ trans, const void* __restrict__ mask,
    const int* __restrict__ ws_ptr, const float* __restrict__ ws_fwd,
    const float* __restrict__ ws_gold, float* __restrict__ out) {
  __shared__ unsigned char bp[KSTEPS * TT];     // 16320 B
  __shared__ unsigned char path[KSTEPS * TT];   // 16320 B
  __shared__ int entries[8];

  const int b = blockIdx.x;
  const int tid = threadIdx.x;
  const int mode = mask_mode(mask);
  const int lane = tid & 63;
  float* out_decode = out + 1 + NB;

  const int L = seq_length_lane(mask, b, lane, mode);  // same in every wave
  const int steps = L - 2;

  if (tid == 0) out[1 + b] = 0.0f;  // path_score = zeros(B)
  if (b == 0 && tid >= 64 && tid < 128) {
    int t = tid - 64;
    float sf = 0.0f, sg = 0.0f;
    for (int r = 0; r < 4; ++r) { sf += ws_fwd[t + 64 * r]; sg += ws_gold[t + 64 * r]; }
    for (int d = 1; d < 64; d <<= 1) { sf += __shfl_xor(sf, d, 64); sg += __shfl_xor(sg, d, 64); }
    if (t == 0) out[0] = (sf - sg) / 256.0f;
  }

  // ---- parallel bp recompute: thread (g=tid>>5, jj=tid&31) handles k = g, g+16, ...
  {
    const int jj = tid & 31;
    const int g = tid >> 5;
    float Cc[TT];
    unrollN<TT>([&](auto I) { constexpr int ii = I; Cc[ii] = trans[ii * TT + jj]; });
    const float* pb = pstore + (size_t)b * (PQUADS * 128);
    const float* fbb = feats + (size_t)b * (SS * TT);
    for (int k = g; k < KSTEPS; k += 16) {
      if (k < steps) {
        const float* rowp = pb + (k >> 2) * 128 + (k & 3);  // row k, stride-4 floats
        float P[TT];
        unrollN<TT>([&](auto I) { constexpr int ii = I; P[ii] = rowp[ii * 4]; });
        float fj = fbb[(k + 2) * TT + jj];
        float cur[TT];  // fl(fl(f+tr) + p): identical floats to K1's chain
        unrollN<TT>([&](auto I) { constexpr int ii = I; cur[ii] = (fj + Cc[ii]) + P[ii]; });
        float t0 = max3f(cur[0], cur[1], cur[2]);
        float t1 = max3f(cur[3], cur[4], cur[5]);
        float t2 = max3f(cur[6], cur[7], cur[8]);
        float t3 = max3f(cur[9], cur[10], cur[11]);
        float t4 = max3f(cur[12], cur[13], cur[14]);
        float t5 = max3f(cur[15], cur[16], cur[17]);
        float t6 = max3f(cur[18], cur[19], cur[20]);
        float t7 = max3f(cur[21], cur[22], cur[23]);
        float t8 = max3f(cur[24], cur[25], cur[26]);
        float t9 = max3f(cur[27], cur[28], cur[29]);
        float ta = fmaxf(cur[30], cur[31]);
        float vmax = fmaxf(fmaxf(max3f(t0, t1, t2), max3f(t3, t4, t5)),
                           fmaxf(max3f(t6, t7, t8), fmaxf(t9, ta)));
        int bi = 31;  // first-max (descending overwrite-on-equal = jnp.argmax)
        unrollN<TT>([&](auto I) { constexpr int ii = 31 - I; bi = (cur[ii] == vmax) ? ii : bi; });
        bp[k * TT + jj] = (unsigned char)bi;
      } else {
        bp[k * TT + jj] = 0;  // reference masks bps to 0 beyond steps
      }
    }
  }
  __syncthreads();

  // ---- chunked-hypothesis backtrace (each wave = one 64-step chunk)
  const int wave = tid >> 6;
  if (lane < 32) {
    const int lo = wave * 64;
    const int hi = (lo + 64 < KSTEPS) ? (lo + 64) : KSTEPS;
    int ptr = lane;
    for (int k = hi - 1; k >= lo; --k) {
      ptr = bp[k * TT + ptr];
      path[k * TT + lane] = (unsigned char)ptr;
    }
  }
  __syncthreads();

  // compose chunk entries from the top (chunk 7 enters with pointer)
  if (tid == 0) {
    int e = ws_ptr[b];
    for (int c = 7; c >= 0; --c) {
      entries[c] = e;
      e = path[(c * 64) * TT + e];
    }
  }
  __syncthreads();

  // decode row: [0, ptrs[0..509], pointer]
  const int s = tid;
  int val;
  if (s == 0) val = 0;
  else if (s <= KSTEPS) { int k = s - 1; val = path[k * TT + entries[k >> 6]]; }
  else val = ws_ptr[b];
  out_decode[(size_t)b * SS + s] = (float)val;
}

extern "C" void kernel_launch(void* const* d_in, const int* in_sizes, int n_in,
                              void* d_out, int out_size, void* d_ws, size_t ws_size,
                              hipStream_t stream) {
  const float* feats = (const float*)d_in[0];
  const float* trans = (const float*)d_in[1];
  const void* mask = d_in[2];
  const int* tags = (const int*)d_in[3];
  float* out = (float*)d_out;

  unsigned char* ws = (unsigned char*)d_ws;
  const size_t PST_BYTES = (size_t)NB * PQUADS * 128 * 4;  // 16,777,216
  float* pstore = (float*)ws;
  float* ws_fwd = (float*)(ws + PST_BYTES);
  float* ws_gold = (float*)(ws + PST_BYTES + 2048);
  int* ws_ptr = (int*)(ws + PST_BYTES + 4096);

  hipLaunchKernelGGL(crf_main_kernel, dim3(3 * NB), dim3(64), 0, stream,
                     feats, trans, mask, tags, pstore, ws_fwd, ws_gold, ws_ptr);
  hipLaunchKernelGGL(crf_backtrace_kernel, dim3(NB), dim3(512), 0, stream,
                     pstore, feats, trans, mask, ws_ptr, ws_fwd, ws_gold, out);
}